// Round 13
// baseline (84.190 us; speedup 1.0000x reference)
//
#include <hip/hip_runtime.h>
#include <hip/hip_bf16.h>

#define CCH 256      // channels
#define HH 128
#define WW 128
#define SS (HH*WW)   // 16384 pixels per batch
#define NB 8         // batch
#define NK 19        // keypoints
#define STILE 32     // pixels per block
#define NTIL (NB * (SS / STILE))   // 4096 tiles

typedef __attribute__((ext_vector_type(8))) short short8v;   // 8 bf16 = 4 VGPR (MFMA operand)
typedef __attribute__((ext_vector_type(4))) float f32x4;     // MFMA accum
typedef __attribute__((ext_vector_type(2))) float f32x2;     // native float2 (nt-store OK)

static __device__ __forceinline__ unsigned short f2bf(float x) {
    __hip_bfloat16 h = __float2bfloat16(x);
    return *reinterpret_cast<unsigned short*>(&h);
}
static __device__ __forceinline__ float bf2f(unsigned short u) {
    union { unsigned int i; float f; } z; z.i = ((unsigned int)u) << 16; return z.f;
}
static __device__ __forceinline__ float tanh_fast(float x) {
    // 1 - 2/(e^{2x}+1) with v_rcp (tolerance is generous; verified 0.0156)
    float e = __expf(2.f * x);
    return 1.f - 2.f * __builtin_amdgcn_rcpf(e + 1.f);
}
static __device__ __forceinline__ float sigmoid_fast(float z) {
    return __builtin_amdgcn_rcpf(1.f + __expf(-z));
}
// async global->LDS, 16B per lane: LDS dest = base + lane*16 (wave-uniform
// base), global src = per-lane address. VGPR-free staging.
static __device__ __forceinline__ void gload_lds16(const float* g, float* l) {
    __builtin_amdgcn_global_load_lds(
        (const __attribute__((address_space(1))) void*)g,
        (__attribute__((address_space(3))) void*)l, 16, 0, 0);
}

// ---------------------------------------------------------------------------
// Kernel 1: precompute folded biases, delta weights, keypoint pixels, and
// img_fc_w rearranged to bf16 in MFMA A-fragment order:
//   Wfrag[((ks*16 + ot)*64 + lane)*8 + j] = bf16(W[ot*16 + (lane&15)][ks*32 + (lane>>4)*8 + j])
// ---------------------------------------------------------------------------
__global__ __launch_bounds__(256) void precompute_kernel(
    const float* __restrict__ kf,        // [B,K,3]
    const float* __restrict__ img_fc_w,  // [256,256]
    const float* __restrict__ img_fc_b,  // [256]
    const float* __restrict__ kp_proj_w, // [19,19]
    const float* __restrict__ kp_proj_b, // [19]
    const float* __restrict__ kp_fc_w,   // [256,19]
    const float* __restrict__ kp_fc_b,   // [256]
    float* __restrict__ cb,              // [256] combined bias
    float* __restrict__ delta,           // [256*19]
    int* __restrict__ pix,               // [B*K]
    unsigned short* __restrict__ Wfrag)  // [8*16*64*8]
{
    int t = threadIdx.x;
    {
        float acc = img_fc_b[t] + kp_fc_b[t];
        for (int k2 = 0; k2 < NK; ++k2) acc += kp_fc_w[t * NK + k2] * kp_proj_b[k2];
        cb[t] = acc;
        for (int k = 0; k < NK; ++k) {
            float d = 0.f;
            for (int k2 = 0; k2 < NK; ++k2) d += kp_fc_w[t * NK + k2] * kp_proj_w[k2 * NK + k];
            delta[t * NK + k] = d;
        }
    }
    if (t < NB * NK) {
        float kx = kf[t * 3 + 0], ky = kf[t * 3 + 1], vis = kf[t * 3 + 2];
        int p = -1;
        if (vis > 0.f) {
            int xi = (int)fminf(fmaxf(kx * (1.f / (float)WW), 0.f), (float)(WW - 1));
            int yi = (int)fminf(fmaxf(ky * (1.f / (float)HH), 0.f), (float)(HH - 1));
            p = yi * WW + xi;
        }
        pix[t] = p;
    }
    for (int g = t; g < 8 * 16 * 64; g += 256) {
        int lane = g & 63;
        int ot = (g >> 6) & 15;
        int ks = g >> 10;
        int o = ot * 16 + (lane & 15);
        int c0 = ks * 32 + (lane >> 4) * 8;
#pragma unroll
        for (int j = 0; j < 8; ++j)
            Wfrag[g * 8 + j] = f2bf(img_fc_w[o * CCH + c0 + j]);
    }
}

// ---------------------------------------------------------------------------
// Kernel 2: main fused GEMM + epilogue. 4096 blocks x 512 thr (8 waves).
// R13 = R12 async staging + R8 residency:
//  - phase 1a: global_load_lds stages fp32 tile into Xf (VGPR-free, all in
//    flight at block start)
//  - phase 1b: read-regs -> barrier -> write bf16 swizzled Xl OVERLAYING Xf
//    (Xf dead afterwards) -> LDS total 35KB -> 4 blocks/CU, 100% occupancy
//  - phase 4: bf16 readback from Xl (R10-style), nt f32x2 stores
// ---------------------------------------------------------------------------
__global__ __launch_bounds__(512, 8) void main_kernel(
    const float* __restrict__ img,        // [B,256,16384]
    const unsigned short* __restrict__ Wfrag,
    const float* __restrict__ cb,         // [256]
    const float* __restrict__ aw,         // attn_fc_w [256]
    const float* __restrict__ attn_b,     // [1]
    float* __restrict__ out)              // [B,256,16384]
{
    __shared__ __align__(16) char smem[35840];
    float* Xf = reinterpret_cast<float*>(smem);                 // 32KB fp32 [c][s]
    unsigned short* Xl = reinterpret_cast<unsigned short*>(smem); // 16KB bf16, overlays Xf
    float* partial = reinterpret_cast<float*>(smem + 32768);    // [8][32]
    float* cbl = reinterpret_cast<float*>(smem + 33792);        // [256]
    float* awl = reinterpret_cast<float*>(smem + 34816);        // [256]

    const int t = threadIdx.x;
    const int l = t & 63;        // lane
    const int w = t >> 6;        // wave 0..7

    // XCD-chunked bijective swizzle (4096 % 8 == 0).
    const int bid = blockIdx.x;
    const int swz = (bid & 7) * (NTIL / 8) + (bid >> 3);
    const int b = swz >> 9;                  // 512 tiles per batch
    const int sb = (swz & 511) * STILE;
    const float* imgb = img + (size_t)b * CCH * SS;

    // ---- phase 1a: async stage fp32 tile, 4 insts/wave, zero VGPRs --------
    // inst i of wave w: channels c0..c0+7 (c0 = w*32+i*8), 32 px each.
    // lane l -> global c = c0 + (l>>3), px = (l&7)*4 ; LDS = Xf + c0*32 + l*4.
#pragma unroll
    for (int i = 0; i < 4; ++i) {
        const int c0 = w * 32 + i * 8;
        gload_lds16(imgb + (size_t)(c0 + (l >> 3)) * SS + sb + (l & 7) * 4,
                    &Xf[c0 * STILE]);
    }

    if (t < 256) { cbl[t] = cb[t]; awl[t] = aw[t]; }
    __syncthreads();   // drains async loads (vmcnt 0) + orders cbl/awl

    // ---- phase 1b: transpose via regs; Xl overlays Xf -------------------
    const int sl = t & 31;             // pixel this thread owns
    const int cg16 = (t >> 5) * 16;    // 16 channels this thread owns
    {
        float xv[16];
#pragma unroll
        for (int j = 0; j < 16; ++j) xv[j] = Xf[(cg16 + j) * STILE + sl];
        __syncthreads();               // all Xf reads done before overwrite
#pragma unroll
        for (int h = 0; h < 2; ++h) {
            short8v pk;
#pragma unroll
            for (int e = 0; e < 8; ++e) pk[e] = (short)f2bf(xv[h * 8 + e]);
            int cblk = (cg16 >> 3) + h;
            int idx = sl * 256 + ((cblk ^ (sl & 7)) << 3);
            *reinterpret_cast<short8v*>(&Xl[idx]) = pk;
        }
    }
    __syncthreads();

    // ---- phase 2: K loop, 8 steps of K=32, 4 MFMA per step per wave -------
    f32x4 acc[2][2];
#pragma unroll
    for (int m = 0; m < 2; ++m)
#pragma unroll
        for (int n = 0; n < 2; ++n)
            acc[m][n] = (f32x4){0.f, 0.f, 0.f, 0.f};

#pragma unroll
    for (int ks = 0; ks < 8; ++ks) {
        short8v a[2], bf[2];
#pragma unroll
        for (int m = 0; m < 2; ++m)
            a[m] = *reinterpret_cast<const short8v*>(
                &Wfrag[(((ks * 16 + (w * 2 + m)) * 64) + l) * 8]);
        const int cblk = ks * 4 + (l >> 4);
#pragma unroll
        for (int n = 0; n < 2; ++n) {
            int s = n * 16 + (l & 15);
            bf[n] = *reinterpret_cast<const short8v*>(
                &Xl[s * 256 + ((cblk ^ (s & 7)) << 3)]);
        }
#pragma unroll
        for (int m = 0; m < 2; ++m)
#pragma unroll
            for (int n = 0; n < 2; ++n)
                acc[m][n] = __builtin_amdgcn_mfma_f32_16x16x32_bf16(a[m], bf[n], acc[m][n], 0, 0, 0);
    }

    // ---- phase 3: wave partials of sum_o aw[o]*tanh(T[o,s]+cb[o]) ---------
    // D layout: s = n*16 + (l&15), o = (w*2+m)*16 + (l>>4)*4 + r
    float p2[2];
#pragma unroll
    for (int n = 0; n < 2; ++n) {
        float accp = 0.f;
#pragma unroll
        for (int m = 0; m < 2; ++m)
#pragma unroll
            for (int r = 0; r < 4; ++r) {
                int o = (w * 2 + m) * 16 + ((l >> 4) << 2) + r;
                accp += awl[o] * tanh_fast(acc[m][n][r] + cbl[o]);
            }
        accp += __shfl_xor(accp, 16);
        accp += __shfl_xor(accp, 32);
        p2[n] = accp;
    }
    if (l < 16) {
        partial[w * STILE + l] = p2[0];
        partial[w * STILE + 16 + l] = p2[1];
    }
    __syncthreads();

    // ---- phase 4: per-thread final reduce + bf16 readback + nt stores -----
    {
        const int pq = (t & 15) * 2;      // 2 pixels
        const int cg = t >> 4;            // channel octet (c0 = cg*8)
        const int c0 = cg * 8;
        const float ab = attn_b[0];
        float z0 = ab, z1 = ab;
#pragma unroll
        for (int ww = 0; ww < 8; ++ww) {
            z0 += partial[ww * STILE + pq];
            z1 += partial[ww * STILE + pq + 1];
        }
        float s0v = sigmoid_fast(z0);
        float s1v = sigmoid_fast(z1);

        short8v v0, v1;
        {
            int i0 = pq * 256 + ((cg ^ (pq & 7)) << 3);
            int i1 = (pq + 1) * 256 + ((cg ^ ((pq + 1) & 7)) << 3);
            v0 = *reinterpret_cast<const short8v*>(&Xl[i0]);
            v1 = *reinterpret_cast<const short8v*>(&Xl[i1]);
        }
#pragma unroll
        for (int j = 0; j < 8; ++j) {
            f32x2 o2;
            o2[0] = bf2f((unsigned short)v0[j]) * s0v;
            o2[1] = bf2f((unsigned short)v1[j]) * s1v;
            __builtin_nontemporal_store(o2, reinterpret_cast<f32x2*>(
                out + (size_t)(b * CCH + c0 + j) * SS + sb + pq));
        }
    }
}

// ---------------------------------------------------------------------------
// Kernel 3: exact fp32 fixup for keypoint pixels (<=152). One block per (b,k).
// ---------------------------------------------------------------------------
__global__ __launch_bounds__(256) void fixup_kernel(
    const float* __restrict__ img,
    const float* __restrict__ img_fc_w,
    const float* __restrict__ aw,
    const float* __restrict__ attn_b,
    const float* __restrict__ cb,
    const float* __restrict__ delta,
    const int* __restrict__ pix,
    float* __restrict__ out)
{
    int bk = blockIdx.x;            // 0..151
    int b = bk / NK;
    int p = pix[bk];
    if (p < 0) return;              // uniform branch, before any barrier
    __shared__ float x[256];
    __shared__ float red[256];
    __shared__ float ssc;
    int t = threadIdx.x;
    const float* imgb = img + (size_t)b * CCH * SS;
    x[t] = imgb[(size_t)t * SS + p];
    __syncthreads();
    float dsum = 0.f;
    for (int k2 = 0; k2 < NK; ++k2)
        if (pix[b * NK + k2] == p) dsum += delta[t * NK + k2];
    float acc = cb[t] + dsum;
    for (int c = 0; c < CCH; ++c) acc += img_fc_w[t * CCH + c] * x[c];
    red[t] = aw[t] * tanh_fast(acc);
    __syncthreads();
    for (int off = 128; off > 0; off >>= 1) {
        if (t < off) red[t] += red[t + off];
        __syncthreads();
    }
    if (t == 0) ssc = sigmoid_fast(red[0] + attn_b[0]);
    __syncthreads();
    __builtin_nontemporal_store(x[t] * ssc, out + (size_t)(b * CCH + t) * SS + p);
}

// ---------------------------------------------------------------------------
extern "C" void kernel_launch(void* const* d_in, const int* in_sizes, int n_in,
                              void* d_out, int out_size, void* d_ws, size_t ws_size,
                              hipStream_t stream) {
    (void)in_sizes; (void)n_in; (void)out_size; (void)ws_size;
    const float* img       = (const float*)d_in[0];
    const float* kf        = (const float*)d_in[1];
    const float* img_fc_w  = (const float*)d_in[2];
    const float* img_fc_b  = (const float*)d_in[3];
    const float* kp_proj_w = (const float*)d_in[4];
    const float* kp_proj_b = (const float*)d_in[5];
    const float* kp_fc_w   = (const float*)d_in[6];
    const float* kp_fc_b   = (const float*)d_in[7];
    const float* attn_fc_w = (const float*)d_in[8];
    const float* attn_fc_b = (const float*)d_in[9];
    float* out = (float*)d_out;

    char* ws = (char*)d_ws;
    float* cb             = (float*)(ws);            // 256 f  ->   1024 B
    float* delta          = (float*)(ws + 1024);     // 4864 f -> 19456 B
    int*   pix            = (int*)  (ws + 20480);    // 152 i  ->   608 B
    unsigned short* Wfrag = (unsigned short*)(ws + 21504); // 131072 B

    precompute_kernel<<<1, 256, 0, stream>>>(kf, img_fc_w, img_fc_b, kp_proj_w,
                                             kp_proj_b, kp_fc_w, kp_fc_b,
                                             cb, delta, pix, Wfrag);
    main_kernel<<<NTIL, 512, 0, stream>>>(img, Wfrag, cb,
                                          attn_fc_w, attn_fc_b, out);
    fixup_kernel<<<NB * NK, 256, 0, stream>>>(img, img_fc_w, attn_fc_w, attn_fc_b,
                                              cb, delta, pix, out);
}

// Round 14
// 77.264 us; speedup vs baseline: 1.0896x; 1.0896x over previous
//
#include <hip/hip_runtime.h>
#include <hip/hip_bf16.h>

#define CCH 256      // channels
#define HH 128
#define WW 128
#define SS (HH*WW)   // 16384 pixels per batch
#define NB 8         // batch
#define NK 19        // keypoints
#define STILE 32     // pixels per block
#define NTIL (NB * (SS / STILE))   // 4096 tiles

typedef __attribute__((ext_vector_type(8))) short short8v;   // 8 bf16 = 4 VGPR (MFMA operand)
typedef __attribute__((ext_vector_type(4))) float f32x4;     // MFMA accum
typedef __attribute__((ext_vector_type(2))) float f32x2;     // native float2 (nt-store OK)

static __device__ __forceinline__ unsigned short f2bf(float x) {
    __hip_bfloat16 h = __float2bfloat16(x);
    return *reinterpret_cast<unsigned short*>(&h);
}
static __device__ __forceinline__ float bf2f(unsigned short u) {
    union { unsigned int i; float f; } z; z.i = ((unsigned int)u) << 16; return z.f;
}
static __device__ __forceinline__ float tanh_fast(float x) {
    // 1 - 2/(e^{2x}+1) with v_rcp (tolerance is generous; verified 0.0156)
    float e = __expf(2.f * x);
    return 1.f - 2.f * __builtin_amdgcn_rcpf(e + 1.f);
}
static __device__ __forceinline__ float sigmoid_fast(float z) {
    return __builtin_amdgcn_rcpf(1.f + __expf(-z));
}
// async global->LDS, 16B per lane: LDS dest = base + lane*16 (wave-uniform
// base), global src = per-lane address. VGPR-free staging.
static __device__ __forceinline__ void gload_lds16(const float* g, float* l) {
    __builtin_amdgcn_global_load_lds(
        (const __attribute__((address_space(1))) void*)g,
        (__attribute__((address_space(3))) void*)l, 16, 0, 0);
}

// ---------------------------------------------------------------------------
// Kernel 1: precompute folded biases, delta weights, keypoint pixels, and
// img_fc_w rearranged to bf16 in MFMA A-fragment order:
//   Wfrag[((ks*16 + ot)*64 + lane)*8 + j] = bf16(W[ot*16 + (lane&15)][ks*32 + (lane>>4)*8 + j])
// ---------------------------------------------------------------------------
__global__ __launch_bounds__(256) void precompute_kernel(
    const float* __restrict__ kf,        // [B,K,3]
    const float* __restrict__ img_fc_w,  // [256,256]
    const float* __restrict__ img_fc_b,  // [256]
    const float* __restrict__ kp_proj_w, // [19,19]
    const float* __restrict__ kp_proj_b, // [19]
    const float* __restrict__ kp_fc_w,   // [256,19]
    const float* __restrict__ kp_fc_b,   // [256]
    float* __restrict__ cb,              // [256] combined bias
    float* __restrict__ delta,           // [256*19]
    int* __restrict__ pix,               // [B*K]
    unsigned short* __restrict__ Wfrag)  // [8*16*64*8]
{
    int t = threadIdx.x;
    {
        float acc = img_fc_b[t] + kp_fc_b[t];
        for (int k2 = 0; k2 < NK; ++k2) acc += kp_fc_w[t * NK + k2] * kp_proj_b[k2];
        cb[t] = acc;
        for (int k = 0; k < NK; ++k) {
            float d = 0.f;
            for (int k2 = 0; k2 < NK; ++k2) d += kp_fc_w[t * NK + k2] * kp_proj_w[k2 * NK + k];
            delta[t * NK + k] = d;
        }
    }
    if (t < NB * NK) {
        float kx = kf[t * 3 + 0], ky = kf[t * 3 + 1], vis = kf[t * 3 + 2];
        int p = -1;
        if (vis > 0.f) {
            int xi = (int)fminf(fmaxf(kx * (1.f / (float)WW), 0.f), (float)(WW - 1));
            int yi = (int)fminf(fmaxf(ky * (1.f / (float)HH), 0.f), (float)(HH - 1));
            p = yi * WW + xi;
        }
        pix[t] = p;
    }
    for (int g = t; g < 8 * 16 * 64; g += 256) {
        int lane = g & 63;
        int ot = (g >> 6) & 15;
        int ks = g >> 10;
        int o = ot * 16 + (lane & 15);
        int c0 = ks * 32 + (lane >> 4) * 8;
#pragma unroll
        for (int j = 0; j < 8; ++j)
            Wfrag[g * 8 + j] = f2bf(img_fc_w[o * CCH + c0 + j]);
    }
}

// ---------------------------------------------------------------------------
// Kernel 2: main fused GEMM + epilogue. 4096 blocks x 512 thr (8 waves).
// R14 = R13 + PERSISTENT A-FRAGMENTS:
//  - the wave's 16 A-fragments (2 o-frags x 8 K-steps, 64 VGPR) are loaded
//    from L2 BEFORE the staging barrier -> their latency overlaps the async
//    img staging; the K-loop becomes pure LDS+MFMA (zero global accesses).
//    Isolates the "K-loop A-load L2 latency" variable vs R12/R13.
//  - everything else (async gload_lds staging, overlay transpose, epilogue,
//    nt stores) identical to R13.
// ---------------------------------------------------------------------------
__global__ __launch_bounds__(512, 4) void main_kernel(
    const float* __restrict__ img,        // [B,256,16384]
    const unsigned short* __restrict__ Wfrag,
    const float* __restrict__ cb,         // [256]
    const float* __restrict__ aw,         // attn_fc_w [256]
    const float* __restrict__ attn_b,     // [1]
    float* __restrict__ out)              // [B,256,16384]
{
    __shared__ __align__(16) char smem[35840];
    float* Xf = reinterpret_cast<float*>(smem);                 // 32KB fp32 [c][s]
    unsigned short* Xl = reinterpret_cast<unsigned short*>(smem); // 16KB bf16, overlays Xf
    float* partial = reinterpret_cast<float*>(smem + 32768);    // [8][32]
    float* cbl = reinterpret_cast<float*>(smem + 33792);        // [256]
    float* awl = reinterpret_cast<float*>(smem + 34816);        // [256]

    const int t = threadIdx.x;
    const int l = t & 63;        // lane
    const int w = t >> 6;        // wave 0..7

    // XCD-chunked bijective swizzle (4096 % 8 == 0).
    const int bid = blockIdx.x;
    const int swz = (bid & 7) * (NTIL / 8) + (bid >> 3);
    const int b = swz >> 9;                  // 512 tiles per batch
    const int sb = (swz & 511) * STILE;
    const float* imgb = img + (size_t)b * CCH * SS;

    // ---- phase 0: persistent A-fragments, issued first (L2-hot) -----------
    short8v areg[2][8];
#pragma unroll
    for (int ks = 0; ks < 8; ++ks)
#pragma unroll
        for (int m = 0; m < 2; ++m)
            areg[m][ks] = *reinterpret_cast<const short8v*>(
                &Wfrag[(((ks * 16 + (w * 2 + m)) * 64) + l) * 8]);

    // ---- phase 1a: async stage fp32 tile, 4 insts/wave, zero VGPRs --------
    // inst i of wave w: channels c0..c0+7 (c0 = w*32+i*8), 32 px each.
    // lane l -> global c = c0 + (l>>3), px = (l&7)*4 ; LDS = Xf + c0*32 + l*4.
#pragma unroll
    for (int i = 0; i < 4; ++i) {
        const int c0 = w * 32 + i * 8;
        gload_lds16(imgb + (size_t)(c0 + (l >> 3)) * SS + sb + (l & 7) * 4,
                    &Xf[c0 * STILE]);
    }

    if (t < 256) { cbl[t] = cb[t]; awl[t] = aw[t]; }
    __syncthreads();   // drains async loads + A-loads (overlapped)

    // ---- phase 1b: transpose via regs; Xl overlays Xf ---------------------
    const int sl = t & 31;             // pixel this thread owns
    const int cg16 = (t >> 5) * 16;    // 16 channels this thread owns
    {
        float xv[16];
#pragma unroll
        for (int j = 0; j < 16; ++j) xv[j] = Xf[(cg16 + j) * STILE + sl];
        __syncthreads();               // all Xf reads done before overwrite
#pragma unroll
        for (int h = 0; h < 2; ++h) {
            short8v pk;
#pragma unroll
            for (int e = 0; e < 8; ++e) pk[e] = (short)f2bf(xv[h * 8 + e]);
            int cblk = (cg16 >> 3) + h;
            int idx = sl * 256 + ((cblk ^ (sl & 7)) << 3);
            *reinterpret_cast<short8v*>(&Xl[idx]) = pk;
        }
    }
    __syncthreads();

    // ---- phase 2: K loop, PURE LDS + MFMA (A in registers) ----------------
    f32x4 acc[2][2];
#pragma unroll
    for (int m = 0; m < 2; ++m)
#pragma unroll
        for (int n = 0; n < 2; ++n)
            acc[m][n] = (f32x4){0.f, 0.f, 0.f, 0.f};

#pragma unroll
    for (int ks = 0; ks < 8; ++ks) {
        const int cblk = ks * 4 + (l >> 4);
        const int s0 = (l & 15), s1 = 16 + (l & 15);
        short8v bf0 = *reinterpret_cast<const short8v*>(
            &Xl[s0 * 256 + ((cblk ^ (s0 & 7)) << 3)]);
        short8v bf1 = *reinterpret_cast<const short8v*>(
            &Xl[s1 * 256 + ((cblk ^ (s1 & 7)) << 3)]);
        acc[0][0] = __builtin_amdgcn_mfma_f32_16x16x32_bf16(areg[0][ks], bf0, acc[0][0], 0, 0, 0);
        acc[1][0] = __builtin_amdgcn_mfma_f32_16x16x32_bf16(areg[1][ks], bf0, acc[1][0], 0, 0, 0);
        acc[0][1] = __builtin_amdgcn_mfma_f32_16x16x32_bf16(areg[0][ks], bf1, acc[0][1], 0, 0, 0);
        acc[1][1] = __builtin_amdgcn_mfma_f32_16x16x32_bf16(areg[1][ks], bf1, acc[1][1], 0, 0, 0);
    }

    // ---- phase 3: wave partials of sum_o aw[o]*tanh(T[o,s]+cb[o]) ---------
    // D layout: s = n*16 + (l&15), o = (w*2+m)*16 + (l>>4)*4 + r
    float p2[2];
#pragma unroll
    for (int n = 0; n < 2; ++n) {
        float accp = 0.f;
#pragma unroll
        for (int m = 0; m < 2; ++m)
#pragma unroll
            for (int r = 0; r < 4; ++r) {
                int o = (w * 2 + m) * 16 + ((l >> 4) << 2) + r;
                accp += awl[o] * tanh_fast(acc[m][n][r] + cbl[o]);
            }
        accp += __shfl_xor(accp, 16);
        accp += __shfl_xor(accp, 32);
        p2[n] = accp;
    }
    if (l < 16) {
        partial[w * STILE + l] = p2[0];
        partial[w * STILE + 16 + l] = p2[1];
    }
    __syncthreads();

    // ---- phase 4: per-thread final reduce + bf16 readback + nt stores -----
    {
        const int pq = (t & 15) * 2;      // 2 pixels
        const int cg = t >> 4;            // channel octet (c0 = cg*8)
        const int c0 = cg * 8;
        const float ab = attn_b[0];
        float z0 = ab, z1 = ab;
#pragma unroll
        for (int ww = 0; ww < 8; ++ww) {
            z0 += partial[ww * STILE + pq];
            z1 += partial[ww * STILE + pq + 1];
        }
        float s0v = sigmoid_fast(z0);
        float s1v = sigmoid_fast(z1);

        short8v v0, v1;
        {
            int i0 = pq * 256 + ((cg ^ (pq & 7)) << 3);
            int i1 = (pq + 1) * 256 + ((cg ^ ((pq + 1) & 7)) << 3);
            v0 = *reinterpret_cast<const short8v*>(&Xl[i0]);
            v1 = *reinterpret_cast<const short8v*>(&Xl[i1]);
        }
#pragma unroll
        for (int j = 0; j < 8; ++j) {
            f32x2 o2;
            o2[0] = bf2f((unsigned short)v0[j]) * s0v;
            o2[1] = bf2f((unsigned short)v1[j]) * s1v;
            __builtin_nontemporal_store(o2, reinterpret_cast<f32x2*>(
                out + (size_t)(b * CCH + c0 + j) * SS + sb + pq));
        }
    }
}

// ---------------------------------------------------------------------------
// Kernel 3: exact fp32 fixup for keypoint pixels (<=152). One block per (b,k).
// ---------------------------------------------------------------------------
__global__ __launch_bounds__(256) void fixup_kernel(
    const float* __restrict__ img,
    const float* __restrict__ img_fc_w,
    const float* __restrict__ aw,
    const float* __restrict__ attn_b,
    const float* __restrict__ cb,
    const float* __restrict__ delta,
    const int* __restrict__ pix,
    float* __restrict__ out)
{
    int bk = blockIdx.x;            // 0..151
    int b = bk / NK;
    int p = pix[bk];
    if (p < 0) return;              // uniform branch, before any barrier
    __shared__ float x[256];
    __shared__ float red[256];
    __shared__ float ssc;
    int t = threadIdx.x;
    const float* imgb = img + (size_t)b * CCH * SS;
    x[t] = imgb[(size_t)t * SS + p];
    __syncthreads();
    float dsum = 0.f;
    for (int k2 = 0; k2 < NK; ++k2)
        if (pix[b * NK + k2] == p) dsum += delta[t * NK + k2];
    float acc = cb[t] + dsum;
    for (int c = 0; c < CCH; ++c) acc += img_fc_w[t * CCH + c] * x[c];
    red[t] = aw[t] * tanh_fast(acc);
    __syncthreads();
    for (int off = 128; off > 0; off >>= 1) {
        if (t < off) red[t] += red[t + off];
        __syncthreads();
    }
    if (t == 0) ssc = sigmoid_fast(red[0] + attn_b[0]);
    __syncthreads();
    __builtin_nontemporal_store(x[t] * ssc, out + (size_t)(b * CCH + t) * SS + p);
}

// ---------------------------------------------------------------------------
extern "C" void kernel_launch(void* const* d_in, const int* in_sizes, int n_in,
                              void* d_out, int out_size, void* d_ws, size_t ws_size,
                              hipStream_t stream) {
    (void)in_sizes; (void)n_in; (void)out_size; (void)ws_size;
    const float* img       = (const float*)d_in[0];
    const float* kf        = (const float*)d_in[1];
    const float* img_fc_w  = (const float*)d_in[2];
    const float* img_fc_b  = (const float*)d_in[3];
    const float* kp_proj_w = (const float*)d_in[4];
    const float* kp_proj_b = (const float*)d_in[5];
    const float* kp_fc_w   = (const float*)d_in[6];
    const float* kp_fc_b   = (const float*)d_in[7];
    const float* attn_fc_w = (const float*)d_in[8];
    const float* attn_fc_b = (const float*)d_in[9];
    float* out = (float*)d_out;

    char* ws = (char*)d_ws;
    float* cb             = (float*)(ws);            // 256 f  ->   1024 B
    float* delta          = (float*)(ws + 1024);     // 4864 f -> 19456 B
    int*   pix            = (int*)  (ws + 20480);    // 152 i  ->   608 B
    unsigned short* Wfrag = (unsigned short*)(ws + 21504); // 131072 B

    precompute_kernel<<<1, 256, 0, stream>>>(kf, img_fc_w, img_fc_b, kp_proj_w,
                                             kp_proj_b, kp_fc_w, kp_fc_b,
                                             cb, delta, pix, Wfrag);
    main_kernel<<<NTIL, 512, 0, stream>>>(img, Wfrag, cb,
                                          attn_fc_w, attn_fc_b, out);
    fixup_kernel<<<NB * NK, 256, 0, stream>>>(img, img_fc_w, attn_fc_w, attn_fc_b,
                                              cb, delta, pix, out);
}